// Round 1
// 131.576 us; speedup vs baseline: 1.1598x; 1.1598x over previous
//
#include <hip/hip_runtime.h>
#include <math.h>

#define NNODES 20000
#define NEDGES 320000
#define CDIM   256
#define NC     200
#define NB     2048                 // lerp intervals; Wt rows alloc'd 2112 (33*64)
#define TROWS  2112
#define DRANGE 24.0f
#define DELTA  (DRANGE / (float)NB)
#define INVDEL ((float)NB / DRANGE)
#define NTHR   256
#define RS     264                  // LDS row stride in ushorts (528B)
#define CAP    64                   // bucket capacity per node (max degree ~40)

#define FILLB  ((NEDGES + NTHR - 1) / NTHR)   // 1250
#define PACKB  1248
#define TBLK   (TROWS / 64)                   // 33
#define XW3B   ((NNODES + 63) / 64)           // 313

typedef __attribute__((ext_vector_type(8))) short bf16x8;
typedef __attribute__((ext_vector_type(4))) float f32x4;
typedef __attribute__((ext_vector_type(8))) unsigned short u16x8;

__device__ __forceinline__ unsigned short f2bf(float f) {
    unsigned int u = __float_as_uint(f);
    unsigned int r = (u + 0x7FFFu + ((u >> 16) & 1u)) >> 16;   // RNE
    return (unsigned short)r;
}
__device__ __forceinline__ float bf2f(unsigned short h) {
    return __uint_as_float(((unsigned int)h) << 16);
}
__device__ __forceinline__ float ssp_f(float x) {
    const float LOG2V = 0.6931471805599453f;
    if (x < 14.0f) return __logf(1.0f + __expf(x)) - LOG2V;
    return x - LOG2V;
}

// ---------- fused: fill (edge bucketing) + pack (weight bf16 B-fragments) ----------
// blocks [0, FILLB): per edge, d -> u; bucket-insert {snd, u} at rcv
// blocks [FILLB, FILLB+PACKB): pack w3,w4,w5,w1,w2 -> bf16 B-fragment chunks
//   chunk idx = (kt*4+lg)*256 + col, elem j -> k = kt*32 + lg*8 + j
__global__ __launch_bounds__(NTHR, 8)
void fillpack_kernel(const float* __restrict__ pos,
                     const int* __restrict__ snd,
                     const int* __restrict__ rcv,
                     int* __restrict__ cnt,
                     int2* __restrict__ slots,
                     const float* __restrict__ w3, const float* __restrict__ w4,
                     const float* __restrict__ w5, const float* __restrict__ w1,
                     const float* __restrict__ w2,
                     unsigned short* __restrict__ w3p, unsigned short* __restrict__ w4p,
                     unsigned short* __restrict__ w5p, unsigned short* __restrict__ w1p,
                     unsigned short* __restrict__ w2p)
{
    if (blockIdx.x < FILLB) {
        int e = blockIdx.x * NTHR + threadIdx.x;
        if (e >= NEDGES) return;
        int s = snd[e], r = rcv[e];
        float dx = pos[r * 3 + 0] - pos[s * 3 + 0];
        float dy = pos[r * 3 + 1] - pos[s * 3 + 1];
        float dz = pos[r * 3 + 2] - pos[s * 3 + 2];
        float d = sqrtf(dx * dx + dy * dy + dz * dz);
        float u = fminf(d * INVDEL, (float)NB - 0.001f);
        int rank = atomicAdd(&cnt[r], 1);
        if (rank < CAP) {
            int2 v; v.x = s; v.y = __float_as_int(u);
            slots[(size_t)r * CAP + rank] = v;
        }
    } else {
        int idx = (blockIdx.x - FILLB) * NTHR + threadIdx.x;   // 0 .. 319487
        if (idx < 196608) {
            int m = idx >> 16;
            int r = idx & 65535;
            int j = r & 7, c = (r >> 3) & 255, lg = (r >> 11) & 3, kt = r >> 13;
            int k = kt * 32 + lg * 8 + j;
            const float* w = (m == 0) ? w3 : (m == 1) ? w4 : w5;
            unsigned short* wp = (m == 0) ? w3p : (m == 1) ? w4p : w5p;
            wp[r] = f2bf(w[k * CDIM + c]);
        } else if (idx < 253952) {
            int r = idx - 196608;                        // w1p: 224*256 = 57344
            int j = r & 7, c = (r >> 3) & 255, lg = (r >> 11) & 3, kt = r >> 13;
            int k = kt * 32 + lg * 8 + j;
            w1p[r] = (k < NC) ? f2bf(w1[k * CDIM + c]) : (unsigned short)0;
        } else {
            int r = idx - 253952;                        // w2p: 65536
            int j = r & 7, c = (r >> 3) & 255, lg = (r >> 11) & 3, kt = r >> 13;
            int k = kt * 32 + lg * 8 + j;
            w2p[r] = f2bf(w2[k * CDIM + c]);
        }
    }
}

// ---------- fused: filter table (MFMA) + xw3 = x @ w3 (MFMA) ----------
// blocks [0, TBLK): Wtb[i][n] = bf16(ssp(ssp(rbf@w1+b1)@w2+b2)), 64 bins/block
// blocks [TBLK, TBLK+XW3B): xw3h = bf16(x @ w3), 64 rows/block
__global__ __launch_bounds__(NTHR, 2)
void tablexw3_kernel(const unsigned short* __restrict__ w1p, const float* __restrict__ b1,
                     const unsigned short* __restrict__ w2p, const float* __restrict__ b2,
                     unsigned short* __restrict__ Wtb,
                     const float* __restrict__ x,
                     const unsigned short* __restrict__ w3p,
                     unsigned short* __restrict__ xw3h)
{
    __shared__ unsigned short s_a[64 * RS];
    const int t = threadIdx.x;

    if (blockIdx.x < TBLK) {
        const int m0 = blockIdx.x * 64;
        const float cstep = 20.0f / 199.0f;

        // build rbf rows: thread t -> row t>>2, k range [(t&3)*56, +56)
        {
            int row = t >> 2;
            int k0 = (t & 3) * 56;
            float d = (float)(m0 + row) * DELTA;
            #pragma unroll
            for (int j = 0; j < 56; ++j) {
                int k = k0 + j;
                float dd = d - (float)k * cstep;
                float v = (k < NC) ? __expf(-10.0f * dd * dd) : 0.0f;
                s_a[row * RS + k] = f2bf(v);
            }
        }
        __syncthreads();

        const int l = t & 63, w = t >> 6, lr = l & 15, lg = l >> 4, nb = w * 64;
        f32x4 acc[4][4];
        #pragma unroll
        for (int mt = 0; mt < 4; ++mt)
            #pragma unroll
            for (int nt = 0; nt < 4; ++nt) acc[mt][nt] = (f32x4)0.0f;

        // GEMM1: K = 224
        #pragma unroll 2
        for (int kt = 0; kt < 7; ++kt) {
            bf16x8 a[4];
            #pragma unroll
            for (int mt = 0; mt < 4; ++mt)
                a[mt] = *(const bf16x8*)&s_a[(mt * 16 + lr) * RS + kt * 32 + lg * 8];
            #pragma unroll
            for (int nt = 0; nt < 4; ++nt) {
                bf16x8 b = *(const bf16x8*)&w1p[(size_t)(((kt * 4 + lg) * 256) + nb + nt * 16 + lr) * 8];
                #pragma unroll
                for (int mt = 0; mt < 4; ++mt)
                    acc[mt][nt] = __builtin_amdgcn_mfma_f32_16x16x32_bf16(a[mt], b, acc[mt][nt], 0, 0, 0);
            }
        }
        __syncthreads();

        // h = ssp(acc + b1) -> restage bf16
        #pragma unroll
        for (int nt = 0; nt < 4; ++nt) {
            int col = nb + nt * 16 + lr;
            float bias = b1[col];
            #pragma unroll
            for (int mt = 0; mt < 4; ++mt)
                #pragma unroll
                for (int rr = 0; rr < 4; ++rr)
                    s_a[(mt * 16 + lg * 4 + rr) * RS + col] = f2bf(ssp_f(acc[mt][nt][rr] + bias));
        }
        __syncthreads();

        #pragma unroll
        for (int mt = 0; mt < 4; ++mt)
            #pragma unroll
            for (int nt = 0; nt < 4; ++nt) acc[mt][nt] = (f32x4)0.0f;

        // GEMM2: K = 256
        #pragma unroll 2
        for (int kt = 0; kt < 8; ++kt) {
            bf16x8 a[4];
            #pragma unroll
            for (int mt = 0; mt < 4; ++mt)
                a[mt] = *(const bf16x8*)&s_a[(mt * 16 + lr) * RS + kt * 32 + lg * 8];
            #pragma unroll
            for (int nt = 0; nt < 4; ++nt) {
                bf16x8 b = *(const bf16x8*)&w2p[(size_t)(((kt * 4 + lg) * 256) + nb + nt * 16 + lr) * 8];
                #pragma unroll
                for (int mt = 0; mt < 4; ++mt)
                    acc[mt][nt] = __builtin_amdgcn_mfma_f32_16x16x32_bf16(a[mt], b, acc[mt][nt], 0, 0, 0);
            }
        }

        #pragma unroll
        for (int nt = 0; nt < 4; ++nt) {
            int col = nb + nt * 16 + lr;
            float bias = b2[col];
            #pragma unroll
            for (int mt = 0; mt < 4; ++mt)
                #pragma unroll
                for (int rr = 0; rr < 4; ++rr) {
                    int row = m0 + mt * 16 + lg * 4 + rr;
                    Wtb[(size_t)row * CDIM + col] = f2bf(ssp_f(acc[mt][nt][rr] + bias));
                }
        }
    } else {
        const int m0 = (blockIdx.x - TBLK) * 64;

        {
            int row = t >> 2, c0 = (t & 3) * 64;
            int grow = min(m0 + row, NNODES - 1);
            const float* src = &x[(size_t)grow * CDIM + c0];
            unsigned short* dst = &s_a[row * RS + c0];
            #pragma unroll
            for (int oc = 0; oc < 8; ++oc) {
                float4 a = *(const float4*)&src[oc * 8];
                float4 b = *(const float4*)&src[oc * 8 + 4];
                u16x8 v;
                v[0] = f2bf(a.x); v[1] = f2bf(a.y); v[2] = f2bf(a.z); v[3] = f2bf(a.w);
                v[4] = f2bf(b.x); v[5] = f2bf(b.y); v[6] = f2bf(b.z); v[7] = f2bf(b.w);
                *(u16x8*)&dst[oc * 8] = v;
            }
        }
        __syncthreads();

        const int l = t & 63, w = t >> 6, lr = l & 15, lg = l >> 4, nb = w * 64;
        f32x4 acc[4][4];
        #pragma unroll
        for (int mt = 0; mt < 4; ++mt)
            #pragma unroll
            for (int nt = 0; nt < 4; ++nt) acc[mt][nt] = (f32x4)0.0f;

        #pragma unroll 2
        for (int kt = 0; kt < 8; ++kt) {
            bf16x8 a[4];
            #pragma unroll
            for (int mt = 0; mt < 4; ++mt)
                a[mt] = *(const bf16x8*)&s_a[(mt * 16 + lr) * RS + kt * 32 + lg * 8];
            #pragma unroll
            for (int nt = 0; nt < 4; ++nt) {
                bf16x8 b = *(const bf16x8*)&w3p[(size_t)(((kt * 4 + lg) * 256) + nb + nt * 16 + lr) * 8];
                #pragma unroll
                for (int mt = 0; mt < 4; ++mt)
                    acc[mt][nt] = __builtin_amdgcn_mfma_f32_16x16x32_bf16(a[mt], b, acc[mt][nt], 0, 0, 0);
            }
        }

        #pragma unroll
        for (int nt = 0; nt < 4; ++nt) {
            int col = nb + nt * 16 + lr;
            #pragma unroll
            for (int mt = 0; mt < 4; ++mt)
                #pragma unroll
                for (int rr = 0; rr < 4; ++rr) {
                    int row = m0 + mt * 16 + lg * 4 + rr;
                    if (row < NNODES) xw3h[(size_t)row * CDIM + col] = f2bf(acc[mt][nt][rr]);
                }
        }
    }
}

// ---------- gather: wave per node; two edges in parallel (one per half-wave) -------
// lane l: half h = l>>5, 8 channels c8 = (l&31)*8 (16B loads). At the end the two
// halves' partial sums are combined with a shfl_xor(32) and each lane stores float4.
__device__ __forceinline__ void edge_acc8(int2 sv, const unsigned short* __restrict__ Wtb,
                                          const unsigned short* __restrict__ xw3h,
                                          int c8, float (&acc)[8])
{
    int s = sv.x;
    float u = __int_as_float(sv.y);
    int i = (int)u;
    float fr = u - (float)i;
    u16x8 w0 = *(const u16x8*)&Wtb[(size_t)i * CDIM + c8];
    u16x8 w1 = *(const u16x8*)&Wtb[(size_t)(i + 1) * CDIM + c8];
    u16x8 fh = *(const u16x8*)&xw3h[(size_t)s * CDIM + c8];
    #pragma unroll
    for (int q = 0; q < 8; ++q) {
        float a0 = bf2f(w0[q]);
        float a1 = bf2f(w1[q]);
        acc[q] = fmaf(fmaf(fr, a1 - a0, a0), bf2f(fh[q]), acc[q]);
    }
}

__global__ __launch_bounds__(NTHR, 4)
void gather_kernel(const int* __restrict__ cnt,
                   const int2* __restrict__ slots,
                   const unsigned short* __restrict__ Wtb,
                   const unsigned short* __restrict__ xw3h,
                   float* __restrict__ conv)
{
    const int t = threadIdx.x;
    const int n = blockIdx.x * 4 + (t >> 6);
    const int l = t & 63;
    const int h = l >> 5;             // half-wave id: processes edges j+h
    const int c8 = (l & 31) * 8;      // 8 channels per lane
    const int2* sl = slots + (size_t)n * CAP;
    int deg = cnt[n];
    deg = deg > CAP ? CAP : deg;

    float acc[8];
    #pragma unroll
    for (int q = 0; q < 8; ++q) acc[q] = 0.0f;

    int j = 0;
    for (; j + 8 <= deg; j += 8) {
        int2 s0 = sl[j + 0 + h];
        int2 s1 = sl[j + 2 + h];
        int2 s2 = sl[j + 4 + h];
        int2 s3 = sl[j + 6 + h];
        edge_acc8(s0, Wtb, xw3h, c8, acc);
        edge_acc8(s1, Wtb, xw3h, c8, acc);
        edge_acc8(s2, Wtb, xw3h, c8, acc);
        edge_acc8(s3, Wtb, xw3h, c8, acc);
    }
    for (; j < deg; j += 2) {
        if (j + h < deg) {
            int2 sv = sl[j + h];
            edge_acc8(sv, Wtb, xw3h, c8, acc);
        }
    }

    // combine the two halves (lane l and l^32 hold the same channels)
    #pragma unroll
    for (int q = 0; q < 8; ++q) acc[q] += __shfl_xor(acc[q], 32, 64);

    // each lane writes one aligned float4 (h==0 -> low 4 ch, h==1 -> high 4 ch)
    if (h == 0) {
        *(float4*)&conv[(size_t)n * CDIM + c8] = make_float4(acc[0], acc[1], acc[2], acc[3]);
    } else {
        *(float4*)&conv[(size_t)n * CDIM + c8 + 4] = make_float4(acc[4], acc[5], acc[6], acc[7]);
    }
}

// ---------- node MLP (MFMA): out = x + ssp(conv@w4+b4) @ w5 + b5 ----------
__global__ __launch_bounds__(NTHR, 2)
void node_kernel(const float* __restrict__ conv,
                 const unsigned short* __restrict__ w4p, const float* __restrict__ b4,
                 const unsigned short* __restrict__ w5p, const float* __restrict__ b5,
                 const float* __restrict__ x,
                 float* __restrict__ out)
{
    __shared__ unsigned short s_a[64 * RS];
    const int t = threadIdx.x;
    const int m0 = blockIdx.x * 64;

    {
        int row = t >> 2, c0 = (t & 3) * 64;
        int grow = min(m0 + row, NNODES - 1);
        const float* src = &conv[(size_t)grow * CDIM + c0];
        unsigned short* dst = &s_a[row * RS + c0];
        #pragma unroll
        for (int oc = 0; oc < 8; ++oc) {
            float4 a = *(const float4*)&src[oc * 8];
            float4 b = *(const float4*)&src[oc * 8 + 4];
            u16x8 v;
            v[0] = f2bf(a.x); v[1] = f2bf(a.y); v[2] = f2bf(a.z); v[3] = f2bf(a.w);
            v[4] = f2bf(b.x); v[5] = f2bf(b.y); v[6] = f2bf(b.z); v[7] = f2bf(b.w);
            *(u16x8*)&dst[oc * 8] = v;
        }
    }
    __syncthreads();

    const int l = t & 63, w = t >> 6, lr = l & 15, lg = l >> 4, nb = w * 64;
    f32x4 acc[4][4];
    #pragma unroll
    for (int mt = 0; mt < 4; ++mt)
        #pragma unroll
        for (int nt = 0; nt < 4; ++nt) acc[mt][nt] = (f32x4)0.0f;

    #pragma unroll 2
    for (int kt = 0; kt < 8; ++kt) {
        bf16x8 a[4];
        #pragma unroll
        for (int mt = 0; mt < 4; ++mt)
            a[mt] = *(const bf16x8*)&s_a[(mt * 16 + lr) * RS + kt * 32 + lg * 8];
        #pragma unroll
        for (int nt = 0; nt < 4; ++nt) {
            bf16x8 b = *(const bf16x8*)&w4p[(size_t)(((kt * 4 + lg) * 256) + nb + nt * 16 + lr) * 8];
            #pragma unroll
            for (int mt = 0; mt < 4; ++mt)
                acc[mt][nt] = __builtin_amdgcn_mfma_f32_16x16x32_bf16(a[mt], b, acc[mt][nt], 0, 0, 0);
        }
    }
    __syncthreads();

    #pragma unroll
    for (int nt = 0; nt < 4; ++nt) {
        int col = nb + nt * 16 + lr;
        float bias = b4[col];
        #pragma unroll
        for (int mt = 0; mt < 4; ++mt)
            #pragma unroll
            for (int rr = 0; rr < 4; ++rr)
                s_a[(mt * 16 + lg * 4 + rr) * RS + col] = f2bf(ssp_f(acc[mt][nt][rr] + bias));
    }
    __syncthreads();

    #pragma unroll
    for (int mt = 0; mt < 4; ++mt)
        #pragma unroll
        for (int nt = 0; nt < 4; ++nt) acc[mt][nt] = (f32x4)0.0f;

    #pragma unroll 2
    for (int kt = 0; kt < 8; ++kt) {
        bf16x8 a[4];
        #pragma unroll
        for (int mt = 0; mt < 4; ++mt)
            a[mt] = *(const bf16x8*)&s_a[(mt * 16 + lr) * RS + kt * 32 + lg * 8];
        #pragma unroll
        for (int nt = 0; nt < 4; ++nt) {
            bf16x8 b = *(const bf16x8*)&w5p[(size_t)(((kt * 4 + lg) * 256) + nb + nt * 16 + lr) * 8];
            #pragma unroll
            for (int mt = 0; mt < 4; ++mt)
                acc[mt][nt] = __builtin_amdgcn_mfma_f32_16x16x32_bf16(a[mt], b, acc[mt][nt], 0, 0, 0);
        }
    }

    #pragma unroll
    for (int nt = 0; nt < 4; ++nt) {
        int col = nb + nt * 16 + lr;
        float bias = b5[col];
        #pragma unroll
        for (int mt = 0; mt < 4; ++mt)
            #pragma unroll
            for (int rr = 0; rr < 4; ++rr) {
                int row = m0 + mt * 16 + lg * 4 + rr;
                if (row < NNODES)
                    out[(size_t)row * CDIM + col] =
                        acc[mt][nt][rr] + bias + x[(size_t)row * CDIM + col];
            }
    }
}

extern "C" void kernel_launch(void* const* d_in, const int* in_sizes, int n_in,
                              void* d_out, int out_size, void* d_ws, size_t ws_size,
                              hipStream_t stream) {
    const float* pos = (const float*)d_in[0];
    const float* x   = (const float*)d_in[1];
    const int*   snd = (const int*)d_in[2];
    const int*   rcv = (const int*)d_in[3];
    const float* w1  = (const float*)d_in[4];
    const float* b1  = (const float*)d_in[5];
    const float* w2  = (const float*)d_in[6];
    const float* b2  = (const float*)d_in[7];
    const float* w3  = (const float*)d_in[8];
    const float* w4  = (const float*)d_in[9];
    const float* b4  = (const float*)d_in[10];
    const float* w5  = (const float*)d_in[11];
    const float* b5  = (const float*)d_in[12];

    float* out  = (float*)d_out;
    float* conv = out;    // gather writes every conv row exactly once (f32, non-atomic)

    // ws: xw3h bf16 | Wtb bf16 2112x256 | w3p/w4p/w5p | w1p | w2p | cnt | slots
    unsigned char* ws = (unsigned char*)d_ws;
    unsigned short* xw3h = (unsigned short*)ws;
    size_t off = (size_t)NNODES * CDIM * 2;
    unsigned short* Wtb = (unsigned short*)(ws + off); off += (size_t)TROWS * CDIM * 2;
    unsigned short* w3p = (unsigned short*)(ws + off); off += 65536 * 2;
    unsigned short* w4p = (unsigned short*)(ws + off); off += 65536 * 2;
    unsigned short* w5p = (unsigned short*)(ws + off); off += 65536 * 2;
    unsigned short* w1p = (unsigned short*)(ws + off); off += 57344 * 2;
    unsigned short* w2p = (unsigned short*)(ws + off); off += 65536 * 2;
    int* cnt = (int*)(ws + off);                       off += (size_t)NNODES * 4;
    int2* slots = (int2*)(ws + off);

    hipMemsetAsync(cnt, 0, (size_t)NNODES * sizeof(int), stream);

    fillpack_kernel<<<FILLB + PACKB, NTHR, 0, stream>>>(pos, snd, rcv, cnt, slots,
                                                        w3, w4, w5, w1, w2,
                                                        w3p, w4p, w5p, w1p, w2p);
    tablexw3_kernel<<<TBLK + XW3B, NTHR, 0, stream>>>(w1p, b1, w2p, b2, Wtb, x, w3p, xw3h);
    gather_kernel<<<NNODES / 4, NTHR, 0, stream>>>(cnt, slots, Wtb, xw3h, conv);
    node_kernel<<<(NNODES + 63) / 64, NTHR, 0, stream>>>(conv, w4p, b4, w5p, b5, x, out);
}

// Round 2
// 131.433 us; speedup vs baseline: 1.1610x; 1.0011x over previous
//
#include <hip/hip_runtime.h>
#include <math.h>

#define NNODES 20000
#define NEDGES 320000
#define CDIM   256
#define NC     200
#define NB     2048                 // lerp intervals; Wt rows alloc'd 2112 (33*64)
#define TROWS  2112
#define DRANGE 24.0f
#define DELTA  (DRANGE / (float)NB)
#define INVDEL ((float)NB / DRANGE)
#define NTHR   256
#define RS     264                  // LDS row stride in ushorts (528B)
#define CAP    64                   // bucket capacity per node (max degree ~40)

#define FILLB  ((NEDGES + NTHR - 1) / NTHR)   // 1250
#define PACKB  1248
#define TBLK   (TROWS / 64)                   // 33
#define XW3B   ((NNODES + 63) / 64)           // 313

typedef __attribute__((ext_vector_type(8))) short bf16x8;
typedef __attribute__((ext_vector_type(4))) float f32x4;
typedef __attribute__((ext_vector_type(8))) unsigned short u16x8;

__device__ __forceinline__ unsigned short f2bf(float f) {
    unsigned int u = __float_as_uint(f);
    unsigned int r = (u + 0x7FFFu + ((u >> 16) & 1u)) >> 16;   // RNE
    return (unsigned short)r;
}
__device__ __forceinline__ float bf2f(unsigned short h) {
    return __uint_as_float(((unsigned int)h) << 16);
}
__device__ __forceinline__ float ssp_f(float x) {
    const float LOG2V = 0.6931471805599453f;
    if (x < 14.0f) return __logf(1.0f + __expf(x)) - LOG2V;
    return x - LOG2V;
}

// ---------- zero cnt (replaces 42us rocclr fillBuffer) ----------
__global__ __launch_bounds__(NTHR)
void zero_kernel(int4* __restrict__ cnt4)
{
    int i = blockIdx.x * NTHR + threadIdx.x;
    if (i < NNODES / 4) cnt4[i] = make_int4(0, 0, 0, 0);
}

// ---------- fused: fill (edge bucketing) + pack (weight bf16 B-fragments) ----------
__global__ __launch_bounds__(NTHR, 8)
void fillpack_kernel(const float* __restrict__ pos,
                     const int* __restrict__ snd,
                     const int* __restrict__ rcv,
                     int* __restrict__ cnt,
                     int2* __restrict__ slots,
                     const float* __restrict__ w3, const float* __restrict__ w4,
                     const float* __restrict__ w5, const float* __restrict__ w1,
                     const float* __restrict__ w2,
                     unsigned short* __restrict__ w3p, unsigned short* __restrict__ w4p,
                     unsigned short* __restrict__ w5p, unsigned short* __restrict__ w1p,
                     unsigned short* __restrict__ w2p)
{
    if (blockIdx.x < FILLB) {
        int e = blockIdx.x * NTHR + threadIdx.x;
        if (e >= NEDGES) return;
        int s = snd[e], r = rcv[e];
        float dx = pos[r * 3 + 0] - pos[s * 3 + 0];
        float dy = pos[r * 3 + 1] - pos[s * 3 + 1];
        float dz = pos[r * 3 + 2] - pos[s * 3 + 2];
        float d = sqrtf(dx * dx + dy * dy + dz * dz);
        float u = fminf(d * INVDEL, (float)NB - 0.001f);
        int rank = atomicAdd(&cnt[r], 1);
        if (rank < CAP) {
            int2 v; v.x = s; v.y = __float_as_int(u);
            slots[(size_t)r * CAP + rank] = v;
        }
    } else {
        int idx = (blockIdx.x - FILLB) * NTHR + threadIdx.x;   // 0 .. 319487
        if (idx < 196608) {
            int m = idx >> 16;
            int r = idx & 65535;
            int j = r & 7, c = (r >> 3) & 255, lg = (r >> 11) & 3, kt = r >> 13;
            int k = kt * 32 + lg * 8 + j;
            const float* w = (m == 0) ? w3 : (m == 1) ? w4 : w5;
            unsigned short* wp = (m == 0) ? w3p : (m == 1) ? w4p : w5p;
            wp[r] = f2bf(w[k * CDIM + c]);
        } else if (idx < 253952) {
            int r = idx - 196608;                        // w1p: 224*256 = 57344
            int j = r & 7, c = (r >> 3) & 255, lg = (r >> 11) & 3, kt = r >> 13;
            int k = kt * 32 + lg * 8 + j;
            w1p[r] = (k < NC) ? f2bf(w1[k * CDIM + c]) : (unsigned short)0;
        } else {
            int r = idx - 253952;                        // w2p: 65536
            int j = r & 7, c = (r >> 3) & 255, lg = (r >> 11) & 3, kt = r >> 13;
            int k = kt * 32 + lg * 8 + j;
            w2p[r] = f2bf(w2[k * CDIM + c]);
        }
    }
}

// ---------- fused: filter table (MFMA) + xw3 = x @ w3 (MFMA) ----------
__global__ __launch_bounds__(NTHR, 2)
void tablexw3_kernel(const unsigned short* __restrict__ w1p, const float* __restrict__ b1,
                     const unsigned short* __restrict__ w2p, const float* __restrict__ b2,
                     unsigned short* __restrict__ Wtb,
                     const float* __restrict__ x,
                     const unsigned short* __restrict__ w3p,
                     unsigned short* __restrict__ xw3h)
{
    __shared__ unsigned short s_a[64 * RS];
    const int t = threadIdx.x;

    if (blockIdx.x < TBLK) {
        const int m0 = blockIdx.x * 64;
        const float cstep = 20.0f / 199.0f;

        {
            int row = t >> 2;
            int k0 = (t & 3) * 56;
            float d = (float)(m0 + row) * DELTA;
            #pragma unroll
            for (int j = 0; j < 56; ++j) {
                int k = k0 + j;
                float dd = d - (float)k * cstep;
                float v = (k < NC) ? __expf(-10.0f * dd * dd) : 0.0f;
                s_a[row * RS + k] = f2bf(v);
            }
        }
        __syncthreads();

        const int l = t & 63, w = t >> 6, lr = l & 15, lg = l >> 4, nb = w * 64;
        f32x4 acc[4][4];
        #pragma unroll
        for (int mt = 0; mt < 4; ++mt)
            #pragma unroll
            for (int nt = 0; nt < 4; ++nt) acc[mt][nt] = (f32x4)0.0f;

        // GEMM1: K = 224
        #pragma unroll 2
        for (int kt = 0; kt < 7; ++kt) {
            bf16x8 a[4];
            #pragma unroll
            for (int mt = 0; mt < 4; ++mt)
                a[mt] = *(const bf16x8*)&s_a[(mt * 16 + lr) * RS + kt * 32 + lg * 8];
            #pragma unroll
            for (int nt = 0; nt < 4; ++nt) {
                bf16x8 b = *(const bf16x8*)&w1p[(size_t)(((kt * 4 + lg) * 256) + nb + nt * 16 + lr) * 8];
                #pragma unroll
                for (int mt = 0; mt < 4; ++mt)
                    acc[mt][nt] = __builtin_amdgcn_mfma_f32_16x16x32_bf16(a[mt], b, acc[mt][nt], 0, 0, 0);
            }
        }
        __syncthreads();

        #pragma unroll
        for (int nt = 0; nt < 4; ++nt) {
            int col = nb + nt * 16 + lr;
            float bias = b1[col];
            #pragma unroll
            for (int mt = 0; mt < 4; ++mt)
                #pragma unroll
                for (int rr = 0; rr < 4; ++rr)
                    s_a[(mt * 16 + lg * 4 + rr) * RS + col] = f2bf(ssp_f(acc[mt][nt][rr] + bias));
        }
        __syncthreads();

        #pragma unroll
        for (int mt = 0; mt < 4; ++mt)
            #pragma unroll
            for (int nt = 0; nt < 4; ++nt) acc[mt][nt] = (f32x4)0.0f;

        // GEMM2: K = 256
        #pragma unroll 2
        for (int kt = 0; kt < 8; ++kt) {
            bf16x8 a[4];
            #pragma unroll
            for (int mt = 0; mt < 4; ++mt)
                a[mt] = *(const bf16x8*)&s_a[(mt * 16 + lr) * RS + kt * 32 + lg * 8];
            #pragma unroll
            for (int nt = 0; nt < 4; ++nt) {
                bf16x8 b = *(const bf16x8*)&w2p[(size_t)(((kt * 4 + lg) * 256) + nb + nt * 16 + lr) * 8];
                #pragma unroll
                for (int mt = 0; mt < 4; ++mt)
                    acc[mt][nt] = __builtin_amdgcn_mfma_f32_16x16x32_bf16(a[mt], b, acc[mt][nt], 0, 0, 0);
            }
        }

        #pragma unroll
        for (int nt = 0; nt < 4; ++nt) {
            int col = nb + nt * 16 + lr;
            float bias = b2[col];
            #pragma unroll
            for (int mt = 0; mt < 4; ++mt)
                #pragma unroll
                for (int rr = 0; rr < 4; ++rr) {
                    int row = m0 + mt * 16 + lg * 4 + rr;
                    Wtb[(size_t)row * CDIM + col] = f2bf(ssp_f(acc[mt][nt][rr] + bias));
                }
        }
    } else {
        const int m0 = (blockIdx.x - TBLK) * 64;

        {
            int row = t >> 2, c0 = (t & 3) * 64;
            int grow = min(m0 + row, NNODES - 1);
            const float* src = &x[(size_t)grow * CDIM + c0];
            unsigned short* dst = &s_a[row * RS + c0];
            #pragma unroll
            for (int oc = 0; oc < 8; ++oc) {
                float4 a = *(const float4*)&src[oc * 8];
                float4 b = *(const float4*)&src[oc * 8 + 4];
                u16x8 v;
                v[0] = f2bf(a.x); v[1] = f2bf(a.y); v[2] = f2bf(a.z); v[3] = f2bf(a.w);
                v[4] = f2bf(b.x); v[5] = f2bf(b.y); v[6] = f2bf(b.z); v[7] = f2bf(b.w);
                *(u16x8*)&dst[oc * 8] = v;
            }
        }
        __syncthreads();

        const int l = t & 63, w = t >> 6, lr = l & 15, lg = l >> 4, nb = w * 64;
        f32x4 acc[4][4];
        #pragma unroll
        for (int mt = 0; mt < 4; ++mt)
            #pragma unroll
            for (int nt = 0; nt < 4; ++nt) acc[mt][nt] = (f32x4)0.0f;

        #pragma unroll 2
        for (int kt = 0; kt < 8; ++kt) {
            bf16x8 a[4];
            #pragma unroll
            for (int mt = 0; mt < 4; ++mt)
                a[mt] = *(const bf16x8*)&s_a[(mt * 16 + lr) * RS + kt * 32 + lg * 8];
            #pragma unroll
            for (int nt = 0; nt < 4; ++nt) {
                bf16x8 b = *(const bf16x8*)&w3p[(size_t)(((kt * 4 + lg) * 256) + nb + nt * 16 + lr) * 8];
                #pragma unroll
                for (int mt = 0; mt < 4; ++mt)
                    acc[mt][nt] = __builtin_amdgcn_mfma_f32_16x16x32_bf16(a[mt], b, acc[mt][nt], 0, 0, 0);
            }
        }

        #pragma unroll
        for (int nt = 0; nt < 4; ++nt) {
            int col = nb + nt * 16 + lr;
            #pragma unroll
            for (int mt = 0; mt < 4; ++mt)
                #pragma unroll
                for (int rr = 0; rr < 4; ++rr) {
                    int row = m0 + mt * 16 + lg * 4 + rr;
                    if (row < NNODES) xw3h[(size_t)row * CDIM + col] = f2bf(acc[mt][nt][rr]);
                }
        }
    }
}

// ---------- gather: wave per node; two edges in parallel (one per half-wave) -------
// Batched: 8 edges (4 per half) per iteration; 12x16B loads issued before any FMA;
// slot descriptors for the NEXT batch are prefetched during the current one.
__global__ __launch_bounds__(NTHR, 4)
void gather_kernel(const int* __restrict__ cnt,
                   const int2* __restrict__ slots,
                   const unsigned short* __restrict__ Wtb,
                   const unsigned short* __restrict__ xw3h,
                   float* __restrict__ conv)
{
    const int t = threadIdx.x;
    const int n = blockIdx.x * 4 + (t >> 6);
    const int l = t & 63;
    const int h = l >> 5;             // half-wave id: processes edges 2k+h
    const int c8 = (l & 31) * 8;      // 8 channels per lane
    const int2* sl = slots + (size_t)n * CAP;
    int deg = cnt[n];
    deg = deg > CAP ? CAP : deg;

    float acc[8];
    #pragma unroll
    for (int q = 0; q < 8; ++q) acc[q] = 0.0f;

    const int nbat = deg >> 3;        // full 8-edge batches

    int2 d0, d1, d2, d3;
    if (nbat > 0) {
        d0 = sl[0 + h]; d1 = sl[2 + h]; d2 = sl[4 + h]; d3 = sl[6 + h];
    }

    for (int b = 0; b < nbat; ++b) {
        int2 c0 = d0, c1 = d1, c2 = d2, c3 = d3;
        if (b + 1 < nbat) {           // wave-uniform branch
            const int2* p = sl + (b + 1) * 8;
            d0 = p[0 + h]; d1 = p[2 + h]; d2 = p[4 + h]; d3 = p[6 + h];
        }

        // ---- load phase: 12 x 16B in flight ----
        float u0 = __int_as_float(c0.y), u1 = __int_as_float(c1.y);
        float u2 = __int_as_float(c2.y), u3 = __int_as_float(c3.y);
        int i0 = (int)u0, i1 = (int)u1, i2 = (int)u2, i3 = (int)u3;
        float fr0 = u0 - (float)i0, fr1 = u1 - (float)i1;
        float fr2 = u2 - (float)i2, fr3 = u3 - (float)i3;

        u16x8 w0a = *(const u16x8*)&Wtb[(size_t)i0 * CDIM + c8];
        u16x8 w1a = *(const u16x8*)&Wtb[(size_t)(i0 + 1) * CDIM + c8];
        u16x8 fha = *(const u16x8*)&xw3h[(size_t)c0.x * CDIM + c8];
        u16x8 w0b = *(const u16x8*)&Wtb[(size_t)i1 * CDIM + c8];
        u16x8 w1b = *(const u16x8*)&Wtb[(size_t)(i1 + 1) * CDIM + c8];
        u16x8 fhb = *(const u16x8*)&xw3h[(size_t)c1.x * CDIM + c8];
        u16x8 w0c = *(const u16x8*)&Wtb[(size_t)i2 * CDIM + c8];
        u16x8 w1c = *(const u16x8*)&Wtb[(size_t)(i2 + 1) * CDIM + c8];
        u16x8 fhc = *(const u16x8*)&xw3h[(size_t)c2.x * CDIM + c8];
        u16x8 w0d = *(const u16x8*)&Wtb[(size_t)i3 * CDIM + c8];
        u16x8 w1d = *(const u16x8*)&Wtb[(size_t)(i3 + 1) * CDIM + c8];
        u16x8 fhd = *(const u16x8*)&xw3h[(size_t)c3.x * CDIM + c8];

        // ---- compute phase ----
        #pragma unroll
        for (int q = 0; q < 8; ++q) {
            float a0 = bf2f(w0a[q]), a1 = bf2f(w1a[q]);
            acc[q] = fmaf(fmaf(fr0, a1 - a0, a0), bf2f(fha[q]), acc[q]);
        }
        #pragma unroll
        for (int q = 0; q < 8; ++q) {
            float a0 = bf2f(w0b[q]), a1 = bf2f(w1b[q]);
            acc[q] = fmaf(fmaf(fr1, a1 - a0, a0), bf2f(fhb[q]), acc[q]);
        }
        #pragma unroll
        for (int q = 0; q < 8; ++q) {
            float a0 = bf2f(w0c[q]), a1 = bf2f(w1c[q]);
            acc[q] = fmaf(fmaf(fr2, a1 - a0, a0), bf2f(fhc[q]), acc[q]);
        }
        #pragma unroll
        for (int q = 0; q < 8; ++q) {
            float a0 = bf2f(w0d[q]), a1 = bf2f(w1d[q]);
            acc[q] = fmaf(fmaf(fr3, a1 - a0, a0), bf2f(fhd[q]), acc[q]);
        }
    }

    // tail: up to 7 edges
    for (int j = nbat * 8; j < deg; j += 2) {
        if (j + h < deg) {
            int2 sv = sl[j + h];
            float u = __int_as_float(sv.y);
            int i = (int)u;
            float fr = u - (float)i;
            u16x8 w0 = *(const u16x8*)&Wtb[(size_t)i * CDIM + c8];
            u16x8 w1 = *(const u16x8*)&Wtb[(size_t)(i + 1) * CDIM + c8];
            u16x8 fh = *(const u16x8*)&xw3h[(size_t)sv.x * CDIM + c8];
            #pragma unroll
            for (int q = 0; q < 8; ++q) {
                float a0 = bf2f(w0[q]), a1 = bf2f(w1[q]);
                acc[q] = fmaf(fmaf(fr, a1 - a0, a0), bf2f(fh[q]), acc[q]);
            }
        }
    }

    // combine the two halves (lane l and l^32 hold the same channels)
    #pragma unroll
    for (int q = 0; q < 8; ++q) acc[q] += __shfl_xor(acc[q], 32, 64);

    if (h == 0) {
        *(float4*)&conv[(size_t)n * CDIM + c8] = make_float4(acc[0], acc[1], acc[2], acc[3]);
    } else {
        *(float4*)&conv[(size_t)n * CDIM + c8 + 4] = make_float4(acc[4], acc[5], acc[6], acc[7]);
    }
}

// ---------- node MLP (MFMA): out = x + ssp(conv@w4+b4) @ w5 + b5 ----------
__global__ __launch_bounds__(NTHR, 2)
void node_kernel(const float* __restrict__ conv,
                 const unsigned short* __restrict__ w4p, const float* __restrict__ b4,
                 const unsigned short* __restrict__ w5p, const float* __restrict__ b5,
                 const float* __restrict__ x,
                 float* __restrict__ out)
{
    __shared__ unsigned short s_a[64 * RS];
    const int t = threadIdx.x;
    const int m0 = blockIdx.x * 64;

    {
        int row = t >> 2, c0 = (t & 3) * 64;
        int grow = min(m0 + row, NNODES - 1);
        const float* src = &conv[(size_t)grow * CDIM + c0];
        unsigned short* dst = &s_a[row * RS + c0];
        #pragma unroll
        for (int oc = 0; oc < 8; ++oc) {
            float4 a = *(const float4*)&src[oc * 8];
            float4 b = *(const float4*)&src[oc * 8 + 4];
            u16x8 v;
            v[0] = f2bf(a.x); v[1] = f2bf(a.y); v[2] = f2bf(a.z); v[3] = f2bf(a.w);
            v[4] = f2bf(b.x); v[5] = f2bf(b.y); v[6] = f2bf(b.z); v[7] = f2bf(b.w);
            *(u16x8*)&dst[oc * 8] = v;
        }
    }
    __syncthreads();

    const int l = t & 63, w = t >> 6, lr = l & 15, lg = l >> 4, nb = w * 64;
    f32x4 acc[4][4];
    #pragma unroll
    for (int mt = 0; mt < 4; ++mt)
        #pragma unroll
        for (int nt = 0; nt < 4; ++nt) acc[mt][nt] = (f32x4)0.0f;

    #pragma unroll 2
    for (int kt = 0; kt < 8; ++kt) {
        bf16x8 a[4];
        #pragma unroll
        for (int mt = 0; mt < 4; ++mt)
            a[mt] = *(const bf16x8*)&s_a[(mt * 16 + lr) * RS + kt * 32 + lg * 8];
        #pragma unroll
        for (int nt = 0; nt < 4; ++nt) {
            bf16x8 b = *(const bf16x8*)&w4p[(size_t)(((kt * 4 + lg) * 256) + nb + nt * 16 + lr) * 8];
            #pragma unroll
            for (int mt = 0; mt < 4; ++mt)
                acc[mt][nt] = __builtin_amdgcn_mfma_f32_16x16x32_bf16(a[mt], b, acc[mt][nt], 0, 0, 0);
        }
    }
    __syncthreads();

    #pragma unroll
    for (int nt = 0; nt < 4; ++nt) {
        int col = nb + nt * 16 + lr;
        float bias = b4[col];
        #pragma unroll
        for (int mt = 0; mt < 4; ++mt)
            #pragma unroll
            for (int rr = 0; rr < 4; ++rr)
                s_a[(mt * 16 + lg * 4 + rr) * RS + col] = f2bf(ssp_f(acc[mt][nt][rr] + bias));
    }
    __syncthreads();

    #pragma unroll
    for (int mt = 0; mt < 4; ++mt)
        #pragma unroll
        for (int nt = 0; nt < 4; ++nt) acc[mt][nt] = (f32x4)0.0f;

    #pragma unroll 2
    for (int kt = 0; kt < 8; ++kt) {
        bf16x8 a[4];
        #pragma unroll
        for (int mt = 0; mt < 4; ++mt)
            a[mt] = *(const bf16x8*)&s_a[(mt * 16 + lr) * RS + kt * 32 + lg * 8];
        #pragma unroll
        for (int nt = 0; nt < 4; ++nt) {
            bf16x8 b = *(const bf16x8*)&w5p[(size_t)(((kt * 4 + lg) * 256) + nb + nt * 16 + lr) * 8];
            #pragma unroll
            for (int mt = 0; mt < 4; ++mt)
                acc[mt][nt] = __builtin_amdgcn_mfma_f32_16x16x32_bf16(a[mt], b, acc[mt][nt], 0, 0, 0);
        }
    }

    #pragma unroll
    for (int nt = 0; nt < 4; ++nt) {
        int col = nb + nt * 16 + lr;
        float bias = b5[col];
        #pragma unroll
        for (int mt = 0; mt < 4; ++mt)
            #pragma unroll
            for (int rr = 0; rr < 4; ++rr) {
                int row = m0 + mt * 16 + lg * 4 + rr;
                if (row < NNODES)
                    out[(size_t)row * CDIM + col] =
                        acc[mt][nt][rr] + bias + x[(size_t)row * CDIM + col];
            }
    }
}

extern "C" void kernel_launch(void* const* d_in, const int* in_sizes, int n_in,
                              void* d_out, int out_size, void* d_ws, size_t ws_size,
                              hipStream_t stream) {
    const float* pos = (const float*)d_in[0];
    const float* x   = (const float*)d_in[1];
    const int*   snd = (const int*)d_in[2];
    const int*   rcv = (const int*)d_in[3];
    const float* w1  = (const float*)d_in[4];
    const float* b1  = (const float*)d_in[5];
    const float* w2  = (const float*)d_in[6];
    const float* b2  = (const float*)d_in[7];
    const float* w3  = (const float*)d_in[8];
    const float* w4  = (const float*)d_in[9];
    const float* b4  = (const float*)d_in[10];
    const float* w5  = (const float*)d_in[11];
    const float* b5  = (const float*)d_in[12];

    float* out  = (float*)d_out;
    float* conv = out;    // gather writes every conv row exactly once (f32, non-atomic)

    // ws: xw3h bf16 | Wtb bf16 2112x256 | w3p/w4p/w5p | w1p | w2p | cnt | slots
    unsigned char* ws = (unsigned char*)d_ws;
    unsigned short* xw3h = (unsigned short*)ws;
    size_t off = (size_t)NNODES * CDIM * 2;
    unsigned short* Wtb = (unsigned short*)(ws + off); off += (size_t)TROWS * CDIM * 2;
    unsigned short* w3p = (unsigned short*)(ws + off); off += 65536 * 2;
    unsigned short* w4p = (unsigned short*)(ws + off); off += 65536 * 2;
    unsigned short* w5p = (unsigned short*)(ws + off); off += 65536 * 2;
    unsigned short* w1p = (unsigned short*)(ws + off); off += 57344 * 2;
    unsigned short* w2p = (unsigned short*)(ws + off); off += 65536 * 2;
    int* cnt = (int*)(ws + off);                       off += (size_t)NNODES * 4;
    int2* slots = (int2*)(ws + off);

    zero_kernel<<<(NNODES / 4 + NTHR - 1) / NTHR, NTHR, 0, stream>>>((int4*)cnt);
    fillpack_kernel<<<FILLB + PACKB, NTHR, 0, stream>>>(pos, snd, rcv, cnt, slots,
                                                        w3, w4, w5, w1, w2,
                                                        w3p, w4p, w5p, w1p, w2p);
    tablexw3_kernel<<<TBLK + XW3B, NTHR, 0, stream>>>(w1p, b1, w2p, b2, Wtb, x, w3p, xw3h);
    gather_kernel<<<NNODES / 4, NTHR, 0, stream>>>(cnt, slots, Wtb, xw3h, conv);
    node_kernel<<<(NNODES + 63) / 64, NTHR, 0, stream>>>(conv, w4p, b4, w5p, b5, x, out);
}

// Round 3
// 130.633 us; speedup vs baseline: 1.1682x; 1.0061x over previous
//
#include <hip/hip_runtime.h>
#include <math.h>

#define NNODES 20000
#define NEDGES 320000
#define CDIM   256
#define NC     200
#define NB     2048                 // lerp intervals; Wt rows alloc'd 2112 (33*64)
#define TROWS  2112
#define DRANGE 24.0f
#define DELTA  (DRANGE / (float)NB)
#define INVDEL ((float)NB / DRANGE)
#define NTHR   256
#define RS     264                  // LDS row stride in ushorts (528B)
#define CAP    64                   // bucket capacity per node (max degree ~40)

#define FILLB  ((NEDGES + NTHR - 1) / NTHR)   // 1250
#define PACKB  1248
#define TBLK   (TROWS / 64)                   // 33
#define XW3B   ((NNODES + 63) / 64)           // 313

typedef __attribute__((ext_vector_type(8))) short bf16x8;
typedef __attribute__((ext_vector_type(4))) float f32x4;
typedef __attribute__((ext_vector_type(8))) unsigned short u16x8;

__device__ __forceinline__ unsigned short f2bf(float f) {
    unsigned int u = __float_as_uint(f);
    unsigned int r = (u + 0x7FFFu + ((u >> 16) & 1u)) >> 16;   // RNE
    return (unsigned short)r;
}
__device__ __forceinline__ float bf2f(unsigned short h) {
    return __uint_as_float(((unsigned int)h) << 16);
}
__device__ __forceinline__ float ssp_f(float x) {
    const float LOG2V = 0.6931471805599453f;
    if (x < 14.0f) return __logf(1.0f + __expf(x)) - LOG2V;
    return x - LOG2V;
}

// ---------- zero cnt ----------
__global__ __launch_bounds__(NTHR)
void zero_kernel(int4* __restrict__ cnt4)
{
    int i = blockIdx.x * NTHR + threadIdx.x;
    if (i < NNODES / 4) cnt4[i] = make_int4(0, 0, 0, 0);
}

// ---------- fused: fill (edge bucketing) + pack (weight bf16 B-fragments) ----------
__global__ __launch_bounds__(NTHR, 8)
void fillpack_kernel(const float* __restrict__ pos,
                     const int* __restrict__ snd,
                     const int* __restrict__ rcv,
                     int* __restrict__ cnt,
                     int2* __restrict__ slots,
                     const float* __restrict__ w3, const float* __restrict__ w4,
                     const float* __restrict__ w5, const float* __restrict__ w1,
                     const float* __restrict__ w2,
                     unsigned short* __restrict__ w3p, unsigned short* __restrict__ w4p,
                     unsigned short* __restrict__ w5p, unsigned short* __restrict__ w1p,
                     unsigned short* __restrict__ w2p)
{
    if (blockIdx.x < FILLB) {
        int e = blockIdx.x * NTHR + threadIdx.x;
        if (e >= NEDGES) return;
        int s = snd[e], r = rcv[e];
        float dx = pos[r * 3 + 0] - pos[s * 3 + 0];
        float dy = pos[r * 3 + 1] - pos[s * 3 + 1];
        float dz = pos[r * 3 + 2] - pos[s * 3 + 2];
        float d = sqrtf(dx * dx + dy * dy + dz * dz);
        float u = fminf(d * INVDEL, (float)NB - 0.001f);
        int rank = atomicAdd(&cnt[r], 1);
        if (rank < CAP) {
            int2 v; v.x = s; v.y = __float_as_int(u);
            slots[(size_t)r * CAP + rank] = v;
        }
    } else {
        int idx = (blockIdx.x - FILLB) * NTHR + threadIdx.x;   // 0 .. 319487
        if (idx < 196608) {
            int m = idx >> 16;
            int r = idx & 65535;
            int j = r & 7, c = (r >> 3) & 255, lg = (r >> 11) & 3, kt = r >> 13;
            int k = kt * 32 + lg * 8 + j;
            const float* w = (m == 0) ? w3 : (m == 1) ? w4 : w5;
            unsigned short* wp = (m == 0) ? w3p : (m == 1) ? w4p : w5p;
            wp[r] = f2bf(w[k * CDIM + c]);
        } else if (idx < 253952) {
            int r = idx - 196608;                        // w1p: 224*256 = 57344
            int j = r & 7, c = (r >> 3) & 255, lg = (r >> 11) & 3, kt = r >> 13;
            int k = kt * 32 + lg * 8 + j;
            w1p[r] = (k < NC) ? f2bf(w1[k * CDIM + c]) : (unsigned short)0;
        } else {
            int r = idx - 253952;                        // w2p: 65536
            int j = r & 7, c = (r >> 3) & 255, lg = (r >> 11) & 3, kt = r >> 13;
            int k = kt * 32 + lg * 8 + j;
            w2p[r] = f2bf(w2[k * CDIM + c]);
        }
    }
}

// ---------- fused: filter table (MFMA) + xw3 = x @ w3 (MFMA) ----------
__global__ __launch_bounds__(NTHR, 2)
void tablexw3_kernel(const unsigned short* __restrict__ w1p, const float* __restrict__ b1,
                     const unsigned short* __restrict__ w2p, const float* __restrict__ b2,
                     unsigned short* __restrict__ Wtb,
                     const float* __restrict__ x,
                     const unsigned short* __restrict__ w3p,
                     unsigned short* __restrict__ xw3h)
{
    __shared__ unsigned short s_a[64 * RS];
    const int t = threadIdx.x;

    if (blockIdx.x < TBLK) {
        const int m0 = blockIdx.x * 64;
        const float cstep = 20.0f / 199.0f;

        {
            int row = t >> 2;
            int k0 = (t & 3) * 56;
            float d = (float)(m0 + row) * DELTA;
            #pragma unroll
            for (int j = 0; j < 56; ++j) {
                int k = k0 + j;
                float dd = d - (float)k * cstep;
                float v = (k < NC) ? __expf(-10.0f * dd * dd) : 0.0f;
                s_a[row * RS + k] = f2bf(v);
            }
        }
        __syncthreads();

        const int l = t & 63, w = t >> 6, lr = l & 15, lg = l >> 4, nb = w * 64;
        f32x4 acc[4][4];
        #pragma unroll
        for (int mt = 0; mt < 4; ++mt)
            #pragma unroll
            for (int nt = 0; nt < 4; ++nt) acc[mt][nt] = (f32x4)0.0f;

        // GEMM1: K = 224
        #pragma unroll 2
        for (int kt = 0; kt < 7; ++kt) {
            bf16x8 a[4];
            #pragma unroll
            for (int mt = 0; mt < 4; ++mt)
                a[mt] = *(const bf16x8*)&s_a[(mt * 16 + lr) * RS + kt * 32 + lg * 8];
            #pragma unroll
            for (int nt = 0; nt < 4; ++nt) {
                bf16x8 b = *(const bf16x8*)&w1p[(size_t)(((kt * 4 + lg) * 256) + nb + nt * 16 + lr) * 8];
                #pragma unroll
                for (int mt = 0; mt < 4; ++mt)
                    acc[mt][nt] = __builtin_amdgcn_mfma_f32_16x16x32_bf16(a[mt], b, acc[mt][nt], 0, 0, 0);
            }
        }
        __syncthreads();

        #pragma unroll
        for (int nt = 0; nt < 4; ++nt) {
            int col = nb + nt * 16 + lr;
            float bias = b1[col];
            #pragma unroll
            for (int mt = 0; mt < 4; ++mt)
                #pragma unroll
                for (int rr = 0; rr < 4; ++rr)
                    s_a[(mt * 16 + lg * 4 + rr) * RS + col] = f2bf(ssp_f(acc[mt][nt][rr] + bias));
        }
        __syncthreads();

        #pragma unroll
        for (int mt = 0; mt < 4; ++mt)
            #pragma unroll
            for (int nt = 0; nt < 4; ++nt) acc[mt][nt] = (f32x4)0.0f;

        // GEMM2: K = 256
        #pragma unroll 2
        for (int kt = 0; kt < 8; ++kt) {
            bf16x8 a[4];
            #pragma unroll
            for (int mt = 0; mt < 4; ++mt)
                a[mt] = *(const bf16x8*)&s_a[(mt * 16 + lr) * RS + kt * 32 + lg * 8];
            #pragma unroll
            for (int nt = 0; nt < 4; ++nt) {
                bf16x8 b = *(const bf16x8*)&w2p[(size_t)(((kt * 4 + lg) * 256) + nb + nt * 16 + lr) * 8];
                #pragma unroll
                for (int mt = 0; mt < 4; ++mt)
                    acc[mt][nt] = __builtin_amdgcn_mfma_f32_16x16x32_bf16(a[mt], b, acc[mt][nt], 0, 0, 0);
            }
        }

        #pragma unroll
        for (int nt = 0; nt < 4; ++nt) {
            int col = nb + nt * 16 + lr;
            float bias = b2[col];
            #pragma unroll
            for (int mt = 0; mt < 4; ++mt)
                #pragma unroll
                for (int rr = 0; rr < 4; ++rr) {
                    int row = m0 + mt * 16 + lg * 4 + rr;
                    Wtb[(size_t)row * CDIM + col] = f2bf(ssp_f(acc[mt][nt][rr] + bias));
                }
        }
    } else {
        const int m0 = (blockIdx.x - TBLK) * 64;

        {
            int row = t >> 2, c0 = (t & 3) * 64;
            int grow = min(m0 + row, NNODES - 1);
            const float* src = &x[(size_t)grow * CDIM + c0];
            unsigned short* dst = &s_a[row * RS + c0];
            #pragma unroll
            for (int oc = 0; oc < 8; ++oc) {
                float4 a = *(const float4*)&src[oc * 8];
                float4 b = *(const float4*)&src[oc * 8 + 4];
                u16x8 v;
                v[0] = f2bf(a.x); v[1] = f2bf(a.y); v[2] = f2bf(a.z); v[3] = f2bf(a.w);
                v[4] = f2bf(b.x); v[5] = f2bf(b.y); v[6] = f2bf(b.z); v[7] = f2bf(b.w);
                *(u16x8*)&dst[oc * 8] = v;
            }
        }
        __syncthreads();

        const int l = t & 63, w = t >> 6, lr = l & 15, lg = l >> 4, nb = w * 64;
        f32x4 acc[4][4];
        #pragma unroll
        for (int mt = 0; mt < 4; ++mt)
            #pragma unroll
            for (int nt = 0; nt < 4; ++nt) acc[mt][nt] = (f32x4)0.0f;

        #pragma unroll 2
        for (int kt = 0; kt < 8; ++kt) {
            bf16x8 a[4];
            #pragma unroll
            for (int mt = 0; mt < 4; ++mt)
                a[mt] = *(const bf16x8*)&s_a[(mt * 16 + lr) * RS + kt * 32 + lg * 8];
            #pragma unroll
            for (int nt = 0; nt < 4; ++nt) {
                bf16x8 b = *(const bf16x8*)&w3p[(size_t)(((kt * 4 + lg) * 256) + nb + nt * 16 + lr) * 8];
                #pragma unroll
                for (int mt = 0; mt < 4; ++mt)
                    acc[mt][nt] = __builtin_amdgcn_mfma_f32_16x16x32_bf16(a[mt], b, acc[mt][nt], 0, 0, 0);
            }
        }

        #pragma unroll
        for (int nt = 0; nt < 4; ++nt) {
            int col = nb + nt * 16 + lr;
            #pragma unroll
            for (int mt = 0; mt < 4; ++mt)
                #pragma unroll
                for (int rr = 0; rr < 4; ++rr) {
                    int row = m0 + mt * 16 + lg * 4 + rr;
                    if (row < NNODES) xw3h[(size_t)row * CDIM + col] = f2bf(acc[mt][nt][rr]);
                }
        }
    }
}

// ---------- gather: wave per node; ALL 64 lanes on one edge, 4 channels/lane -------
// Per edge: 3 x 8B loads/lane (6 VGPRs of data) -> a batch of 8 edges keeps 24 loads
// (48 VGPRs) in flight. Descriptors come from one lane-load per batch, broadcast by
// __shfl -> scalar address math. No cross-lane reduction needed at the end.

#define GDESC(e, src) \
    int   s##e  = __shfl(src.x, e); \
    float u##e  = __int_as_float(__shfl(src.y, e)); \
    int   i##e  = (int)u##e; \
    float fr##e = u##e - (float)i##e;

#define GLOAD(e) \
    ushort4 wa##e = *(const ushort4*)&Wtb[(size_t)i##e * CDIM + c4]; \
    ushort4 wb##e = *(const ushort4*)&Wtb[(size_t)i##e * CDIM + CDIM + c4]; \
    ushort4 fx##e = *(const ushort4*)&xw3h[(size_t)s##e * CDIM + c4];

#define GFMA(e) { \
    float a0 = bf2f(wa##e.x), b0 = bf2f(wb##e.x); \
    float a1 = bf2f(wa##e.y), b1v = bf2f(wb##e.y); \
    float a2 = bf2f(wa##e.z), b2v = bf2f(wb##e.z); \
    float a3 = bf2f(wa##e.w), b3 = bf2f(wb##e.w); \
    acc.x = fmaf(fmaf(fr##e, b0 - a0, a0),  bf2f(fx##e.x), acc.x); \
    acc.y = fmaf(fmaf(fr##e, b1v - a1, a1), bf2f(fx##e.y), acc.y); \
    acc.z = fmaf(fmaf(fr##e, b2v - a2, a2), bf2f(fx##e.z), acc.z); \
    acc.w = fmaf(fmaf(fr##e, b3 - a3, a3),  bf2f(fx##e.w), acc.w); }

__global__ __launch_bounds__(NTHR, 4)
void gather_kernel(const int* __restrict__ cnt,
                   const int2* __restrict__ slots,
                   const unsigned short* __restrict__ Wtb,
                   const unsigned short* __restrict__ xw3h,
                   float* __restrict__ conv)
{
    const int t = threadIdx.x;
    const int n = blockIdx.x * 4 + (t >> 6);
    const int l = t & 63;
    const int c4 = l * 4;
    const int2* sl = slots + (size_t)n * CAP;
    int deg = cnt[n];
    deg = deg > CAP ? CAP : deg;

    float4 acc = make_float4(0.0f, 0.0f, 0.0f, 0.0f);

    int j = 0;
    int2 dsc = (deg >= 8) ? sl[l & 7] : make_int2(0, 0);

    while (j + 8 <= deg) {
        GDESC(0, dsc) GDESC(1, dsc) GDESC(2, dsc) GDESC(3, dsc)
        GDESC(4, dsc) GDESC(5, dsc) GDESC(6, dsc) GDESC(7, dsc)
        if (j + 16 <= deg) dsc = sl[j + 8 + (l & 7)];   // prefetch next batch descriptors
        GLOAD(0) GLOAD(1) GLOAD(2) GLOAD(3)
        GLOAD(4) GLOAD(5) GLOAD(6) GLOAD(7)
        GFMA(0) GFMA(1) GFMA(2) GFMA(3)
        GFMA(4) GFMA(5) GFMA(6) GFMA(7)
        j += 8;
    }

    if (j + 4 <= deg) {
        int2 d4 = sl[j + (l & 3)];
        GDESC(0, d4) GDESC(1, d4) GDESC(2, d4) GDESC(3, d4)
        GLOAD(0) GLOAD(1) GLOAD(2) GLOAD(3)
        GFMA(0) GFMA(1) GFMA(2) GFMA(3)
        j += 4;
    }

    // serial tail (<= 3 edges): issue loads first, then FMAs
    {
        int rem = deg - j;
        if (rem > 0) {
            int2 sv0 = sl[j];
            GDESC(0, sv0)
            GLOAD(0)
            if (rem > 1) {
                int2 sv1 = sl[j + 1];
                GDESC(1, sv1)
                GLOAD(1)
                if (rem > 2) {
                    int2 sv2 = sl[j + 2];
                    GDESC(2, sv2)
                    GLOAD(2)
                    GFMA(2)
                }
                GFMA(1)
            }
            GFMA(0)
        }
    }

    *(float4*)&conv[(size_t)n * CDIM + c4] = acc;
}

// ---------- node MLP (MFMA): out = x + ssp(conv@w4+b4) @ w5 + b5 ----------
__global__ __launch_bounds__(NTHR, 2)
void node_kernel(const float* __restrict__ conv,
                 const unsigned short* __restrict__ w4p, const float* __restrict__ b4,
                 const unsigned short* __restrict__ w5p, const float* __restrict__ b5,
                 const float* __restrict__ x,
                 float* __restrict__ out)
{
    __shared__ unsigned short s_a[64 * RS];
    const int t = threadIdx.x;
    const int m0 = blockIdx.x * 64;

    {
        int row = t >> 2, c0 = (t & 3) * 64;
        int grow = min(m0 + row, NNODES - 1);
        const float* src = &conv[(size_t)grow * CDIM + c0];
        unsigned short* dst = &s_a[row * RS + c0];
        #pragma unroll
        for (int oc = 0; oc < 8; ++oc) {
            float4 a = *(const float4*)&src[oc * 8];
            float4 b = *(const float4*)&src[oc * 8 + 4];
            u16x8 v;
            v[0] = f2bf(a.x); v[1] = f2bf(a.y); v[2] = f2bf(a.z); v[3] = f2bf(a.w);
            v[4] = f2bf(b.x); v[5] = f2bf(b.y); v[6] = f2bf(b.z); v[7] = f2bf(b.w);
            *(u16x8*)&dst[oc * 8] = v;
        }
    }
    __syncthreads();

    const int l = t & 63, w = t >> 6, lr = l & 15, lg = l >> 4, nb = w * 64;
    f32x4 acc[4][4];
    #pragma unroll
    for (int mt = 0; mt < 4; ++mt)
        #pragma unroll
        for (int nt = 0; nt < 4; ++nt) acc[mt][nt] = (f32x4)0.0f;

    #pragma unroll 2
    for (int kt = 0; kt < 8; ++kt) {
        bf16x8 a[4];
        #pragma unroll
        for (int mt = 0; mt < 4; ++mt)
            a[mt] = *(const bf16x8*)&s_a[(mt * 16 + lr) * RS + kt * 32 + lg * 8];
        #pragma unroll
        for (int nt = 0; nt < 4; ++nt) {
            bf16x8 b = *(const bf16x8*)&w4p[(size_t)(((kt * 4 + lg) * 256) + nb + nt * 16 + lr) * 8];
            #pragma unroll
            for (int mt = 0; mt < 4; ++mt)
                acc[mt][nt] = __builtin_amdgcn_mfma_f32_16x16x32_bf16(a[mt], b, acc[mt][nt], 0, 0, 0);
        }
    }
    __syncthreads();

    #pragma unroll
    for (int nt = 0; nt < 4; ++nt) {
        int col = nb + nt * 16 + lr;
        float bias = b4[col];
        #pragma unroll
        for (int mt = 0; mt < 4; ++mt)
            #pragma unroll
            for (int rr = 0; rr < 4; ++rr)
                s_a[(mt * 16 + lg * 4 + rr) * RS + col] = f2bf(ssp_f(acc[mt][nt][rr] + bias));
    }
    __syncthreads();

    #pragma unroll
    for (int mt = 0; mt < 4; ++mt)
        #pragma unroll
        for (int nt = 0; nt < 4; ++nt) acc[mt][nt] = (f32x4)0.0f;

    #pragma unroll 2
    for (int kt = 0; kt < 8; ++kt) {
        bf16x8 a[4];
        #pragma unroll
        for (int mt = 0; mt < 4; ++mt)
            a[mt] = *(const bf16x8*)&s_a[(mt * 16 + lr) * RS + kt * 32 + lg * 8];
        #pragma unroll
        for (int nt = 0; nt < 4; ++nt) {
            bf16x8 b = *(const bf16x8*)&w5p[(size_t)(((kt * 4 + lg) * 256) + nb + nt * 16 + lr) * 8];
            #pragma unroll
            for (int mt = 0; mt < 4; ++mt)
                acc[mt][nt] = __builtin_amdgcn_mfma_f32_16x16x32_bf16(a[mt], b, acc[mt][nt], 0, 0, 0);
        }
    }

    #pragma unroll
    for (int nt = 0; nt < 4; ++nt) {
        int col = nb + nt * 16 + lr;
        float bias = b5[col];
        #pragma unroll
        for (int mt = 0; mt < 4; ++mt)
            #pragma unroll
            for (int rr = 0; rr < 4; ++rr) {
                int row = m0 + mt * 16 + lg * 4 + rr;
                if (row < NNODES)
                    out[(size_t)row * CDIM + col] =
                        acc[mt][nt][rr] + bias + x[(size_t)row * CDIM + col];
            }
    }
}

extern "C" void kernel_launch(void* const* d_in, const int* in_sizes, int n_in,
                              void* d_out, int out_size, void* d_ws, size_t ws_size,
                              hipStream_t stream) {
    const float* pos = (const float*)d_in[0];
    const float* x   = (const float*)d_in[1];
    const int*   snd = (const int*)d_in[2];
    const int*   rcv = (const int*)d_in[3];
    const float* w1  = (const float*)d_in[4];
    const float* b1  = (const float*)d_in[5];
    const float* w2  = (const float*)d_in[6];
    const float* b2  = (const float*)d_in[7];
    const float* w3  = (const float*)d_in[8];
    const float* w4  = (const float*)d_in[9];
    const float* b4  = (const float*)d_in[10];
    const float* w5  = (const float*)d_in[11];
    const float* b5  = (const float*)d_in[12];

    float* out  = (float*)d_out;
    float* conv = out;    // gather writes every conv row exactly once (f32, non-atomic)

    // ws: xw3h bf16 | Wtb bf16 2112x256 | w3p/w4p/w5p | w1p | w2p | cnt | slots
    unsigned char* ws = (unsigned char*)d_ws;
    unsigned short* xw3h = (unsigned short*)ws;
    size_t off = (size_t)NNODES * CDIM * 2;
    unsigned short* Wtb = (unsigned short*)(ws + off); off += (size_t)TROWS * CDIM * 2;
    unsigned short* w3p = (unsigned short*)(ws + off); off += 65536 * 2;
    unsigned short* w4p = (unsigned short*)(ws + off); off += 65536 * 2;
    unsigned short* w5p = (unsigned short*)(ws + off); off += 65536 * 2;
    unsigned short* w1p = (unsigned short*)(ws + off); off += 57344 * 2;
    unsigned short* w2p = (unsigned short*)(ws + off); off += 65536 * 2;
    int* cnt = (int*)(ws + off);                       off += (size_t)NNODES * 4;
    int2* slots = (int2*)(ws + off);

    zero_kernel<<<(NNODES / 4 + NTHR - 1) / NTHR, NTHR, 0, stream>>>((int4*)cnt);
    fillpack_kernel<<<FILLB + PACKB, NTHR, 0, stream>>>(pos, snd, rcv, cnt, slots,
                                                        w3, w4, w5, w1, w2,
                                                        w3p, w4p, w5p, w1p, w2p);
    tablexw3_kernel<<<TBLK + XW3B, NTHR, 0, stream>>>(w1p, b1, w2p, b2, Wtb, x, w3p, xw3h);
    gather_kernel<<<NNODES / 4, NTHR, 0, stream>>>(cnt, slots, Wtb, xw3h, conv);
    node_kernel<<<(NNODES + 63) / 64, NTHR, 0, stream>>>(conv, w4p, b4, w5p, b5, x, out);
}

// Round 4
// 110.646 us; speedup vs baseline: 1.3792x; 1.1806x over previous
//
#include <hip/hip_runtime.h>
#include <math.h>

#define NNODES 20000
#define NEDGES 320000
#define CDIM   256
#define NC     200
#define NB     2048                 // lerp intervals; Wt rows alloc'd 2112 (33*64)
#define TROWS  2112
#define DRANGE 24.0f
#define DELTA  (DRANGE / (float)NB)
#define INVDEL ((float)NB / DRANGE)
#define NTHR   256
#define RS     264                  // LDS row stride in ushorts (528B)
#define CAP    64                   // bucket capacity per node (max degree ~40)
#define NR     32                   // rows per node/xw3 tile (NNODES % 32 == 0)

#define FILLB  ((NEDGES + NTHR - 1) / NTHR)   // 1250
#define PACKB  1248
#define TBLK   (TROWS / 64)                   // 33
#define XW3B   (NNODES / NR)                  // 625
#define NODEB  (NNODES / NR)                  // 625

typedef __attribute__((ext_vector_type(8))) short bf16x8;
typedef __attribute__((ext_vector_type(4))) float f32x4;
typedef __attribute__((ext_vector_type(8))) unsigned short u16x8;

__device__ __forceinline__ unsigned short f2bf(float f) {
    unsigned int u = __float_as_uint(f);
    unsigned int r = (u + 0x7FFFu + ((u >> 16) & 1u)) >> 16;   // RNE
    return (unsigned short)r;
}
__device__ __forceinline__ float bf2f(unsigned short h) {
    return __uint_as_float(((unsigned int)h) << 16);
}
__device__ __forceinline__ float ssp_f(float x) {
    const float LOG2V = 0.6931471805599453f;
    if (x < 14.0f) return __logf(1.0f + __expf(x)) - LOG2V;
    return x - LOG2V;
}

// ---------- zero cnt ----------
__global__ __launch_bounds__(NTHR)
void zero_kernel(int4* __restrict__ cnt4)
{
    int i = blockIdx.x * NTHR + threadIdx.x;
    if (i < NNODES / 4) cnt4[i] = make_int4(0, 0, 0, 0);
}

// ---------- fused: fill (edge bucketing) + pack (weight bf16 B-fragments) ----------
__global__ __launch_bounds__(NTHR, 8)
void fillpack_kernel(const float* __restrict__ pos,
                     const int* __restrict__ snd,
                     const int* __restrict__ rcv,
                     int* __restrict__ cnt,
                     int2* __restrict__ slots,
                     const float* __restrict__ w3, const float* __restrict__ w4,
                     const float* __restrict__ w5, const float* __restrict__ w1,
                     const float* __restrict__ w2,
                     unsigned short* __restrict__ w3p, unsigned short* __restrict__ w4p,
                     unsigned short* __restrict__ w5p, unsigned short* __restrict__ w1p,
                     unsigned short* __restrict__ w2p)
{
    if (blockIdx.x < FILLB) {
        int e = blockIdx.x * NTHR + threadIdx.x;
        if (e >= NEDGES) return;
        int s = snd[e], r = rcv[e];
        float dx = pos[r * 3 + 0] - pos[s * 3 + 0];
        float dy = pos[r * 3 + 1] - pos[s * 3 + 1];
        float dz = pos[r * 3 + 2] - pos[s * 3 + 2];
        float d = sqrtf(dx * dx + dy * dy + dz * dz);
        float u = fminf(d * INVDEL, (float)NB - 0.001f);
        int rank = atomicAdd(&cnt[r], 1);
        if (rank < CAP) {
            int2 v; v.x = s; v.y = __float_as_int(u);
            slots[(size_t)r * CAP + rank] = v;
        }
    } else {
        int idx = (blockIdx.x - FILLB) * NTHR + threadIdx.x;   // 0 .. 319487
        if (idx < 196608) {
            int m = idx >> 16;
            int r = idx & 65535;
            int j = r & 7, c = (r >> 3) & 255, lg = (r >> 11) & 3, kt = r >> 13;
            int k = kt * 32 + lg * 8 + j;
            const float* w = (m == 0) ? w3 : (m == 1) ? w4 : w5;
            unsigned short* wp = (m == 0) ? w3p : (m == 1) ? w4p : w5p;
            wp[r] = f2bf(w[k * CDIM + c]);
        } else if (idx < 253952) {
            int r = idx - 196608;                        // w1p: 224*256 = 57344
            int j = r & 7, c = (r >> 3) & 255, lg = (r >> 11) & 3, kt = r >> 13;
            int k = kt * 32 + lg * 8 + j;
            w1p[r] = (k < NC) ? f2bf(w1[k * CDIM + c]) : (unsigned short)0;
        } else {
            int r = idx - 253952;                        // w2p: 65536
            int j = r & 7, c = (r >> 3) & 255, lg = (r >> 11) & 3, kt = r >> 13;
            int k = kt * 32 + lg * 8 + j;
            w2p[r] = f2bf(w2[k * CDIM + c]);
        }
    }
}

// ---------- fused: filter table (MFMA, 64-bin tiles) + xw3 = x @ w3 (32-row tiles) --
__global__ __launch_bounds__(NTHR, 2)
void tablexw3_kernel(const unsigned short* __restrict__ w1p, const float* __restrict__ b1,
                     const unsigned short* __restrict__ w2p, const float* __restrict__ b2,
                     unsigned short* __restrict__ Wtb,
                     const float* __restrict__ x,
                     const unsigned short* __restrict__ w3p,
                     unsigned short* __restrict__ xw3h)
{
    __shared__ unsigned short s_a[64 * RS];
    const int t = threadIdx.x;

    if (blockIdx.x < TBLK) {
        const int m0 = blockIdx.x * 64;
        const float cstep = 20.0f / 199.0f;

        {
            int row = t >> 2;
            int k0 = (t & 3) * 56;
            float d = (float)(m0 + row) * DELTA;
            #pragma unroll
            for (int j = 0; j < 56; ++j) {
                int k = k0 + j;
                float dd = d - (float)k * cstep;
                float v = (k < NC) ? __expf(-10.0f * dd * dd) : 0.0f;
                s_a[row * RS + k] = f2bf(v);
            }
        }
        __syncthreads();

        const int l = t & 63, w = t >> 6, lr = l & 15, lg = l >> 4, nb = w * 64;
        f32x4 acc[4][4];
        #pragma unroll
        for (int mt = 0; mt < 4; ++mt)
            #pragma unroll
            for (int nt = 0; nt < 4; ++nt) acc[mt][nt] = (f32x4)0.0f;

        // GEMM1: K = 224
        #pragma unroll 2
        for (int kt = 0; kt < 7; ++kt) {
            bf16x8 a[4];
            #pragma unroll
            for (int mt = 0; mt < 4; ++mt)
                a[mt] = *(const bf16x8*)&s_a[(mt * 16 + lr) * RS + kt * 32 + lg * 8];
            #pragma unroll
            for (int nt = 0; nt < 4; ++nt) {
                bf16x8 b = *(const bf16x8*)&w1p[(size_t)(((kt * 4 + lg) * 256) + nb + nt * 16 + lr) * 8];
                #pragma unroll
                for (int mt = 0; mt < 4; ++mt)
                    acc[mt][nt] = __builtin_amdgcn_mfma_f32_16x16x32_bf16(a[mt], b, acc[mt][nt], 0, 0, 0);
            }
        }
        __syncthreads();

        #pragma unroll
        for (int nt = 0; nt < 4; ++nt) {
            int col = nb + nt * 16 + lr;
            float bias = b1[col];
            #pragma unroll
            for (int mt = 0; mt < 4; ++mt)
                #pragma unroll
                for (int rr = 0; rr < 4; ++rr)
                    s_a[(mt * 16 + lg * 4 + rr) * RS + col] = f2bf(ssp_f(acc[mt][nt][rr] + bias));
        }
        __syncthreads();

        #pragma unroll
        for (int mt = 0; mt < 4; ++mt)
            #pragma unroll
            for (int nt = 0; nt < 4; ++nt) acc[mt][nt] = (f32x4)0.0f;

        // GEMM2: K = 256
        #pragma unroll 2
        for (int kt = 0; kt < 8; ++kt) {
            bf16x8 a[4];
            #pragma unroll
            for (int mt = 0; mt < 4; ++mt)
                a[mt] = *(const bf16x8*)&s_a[(mt * 16 + lr) * RS + kt * 32 + lg * 8];
            #pragma unroll
            for (int nt = 0; nt < 4; ++nt) {
                bf16x8 b = *(const bf16x8*)&w2p[(size_t)(((kt * 4 + lg) * 256) + nb + nt * 16 + lr) * 8];
                #pragma unroll
                for (int mt = 0; mt < 4; ++mt)
                    acc[mt][nt] = __builtin_amdgcn_mfma_f32_16x16x32_bf16(a[mt], b, acc[mt][nt], 0, 0, 0);
            }
        }

        #pragma unroll
        for (int nt = 0; nt < 4; ++nt) {
            int col = nb + nt * 16 + lr;
            float bias = b2[col];
            #pragma unroll
            for (int mt = 0; mt < 4; ++mt)
                #pragma unroll
                for (int rr = 0; rr < 4; ++rr) {
                    int row = m0 + mt * 16 + lg * 4 + rr;
                    Wtb[(size_t)row * CDIM + col] = f2bf(ssp_f(acc[mt][nt][rr] + bias));
                }
        }
    } else {
        // xw3: 32-row tiles (NNODES % 32 == 0 -> no row guards)
        const int m0 = (blockIdx.x - TBLK) * NR;

        {
            int row = t >> 3;
            const float* src = &x[(size_t)(m0 + row) * CDIM];
            unsigned short* dst = &s_a[row * RS];
            #pragma unroll
            for (int oc = 0; oc < 4; ++oc) {
                int c0 = oc * 64 + (t & 7) * 8;
                float4 a = *(const float4*)&src[c0];
                float4 b = *(const float4*)&src[c0 + 4];
                u16x8 v;
                v[0] = f2bf(a.x); v[1] = f2bf(a.y); v[2] = f2bf(a.z); v[3] = f2bf(a.w);
                v[4] = f2bf(b.x); v[5] = f2bf(b.y); v[6] = f2bf(b.z); v[7] = f2bf(b.w);
                *(u16x8*)&dst[c0] = v;
            }
        }
        __syncthreads();

        const int l = t & 63, w = t >> 6, lr = l & 15, lg = l >> 4, nb = w * 64;
        f32x4 acc[2][4];
        #pragma unroll
        for (int mt = 0; mt < 2; ++mt)
            #pragma unroll
            for (int nt = 0; nt < 4; ++nt) acc[mt][nt] = (f32x4)0.0f;

        #pragma unroll 2
        for (int kt = 0; kt < 8; ++kt) {
            bf16x8 a[2];
            #pragma unroll
            for (int mt = 0; mt < 2; ++mt)
                a[mt] = *(const bf16x8*)&s_a[(mt * 16 + lr) * RS + kt * 32 + lg * 8];
            #pragma unroll
            for (int nt = 0; nt < 4; ++nt) {
                bf16x8 b = *(const bf16x8*)&w3p[(size_t)(((kt * 4 + lg) * 256) + nb + nt * 16 + lr) * 8];
                #pragma unroll
                for (int mt = 0; mt < 2; ++mt)
                    acc[mt][nt] = __builtin_amdgcn_mfma_f32_16x16x32_bf16(a[mt], b, acc[mt][nt], 0, 0, 0);
            }
        }

        #pragma unroll
        for (int nt = 0; nt < 4; ++nt) {
            int col = nb + nt * 16 + lr;
            #pragma unroll
            for (int mt = 0; mt < 2; ++mt)
                #pragma unroll
                for (int rr = 0; rr < 4; ++rr) {
                    int row = m0 + mt * 16 + lg * 4 + rr;
                    xw3h[(size_t)row * CDIM + col] = f2bf(acc[mt][nt][rr]);
                }
        }
    }
}

// ---------- gather: wave per node; ALL 64 lanes on one edge, 4 channels/lane -------
#define GDESC(e, src) \
    int   s##e  = __shfl(src.x, e); \
    float u##e  = __int_as_float(__shfl(src.y, e)); \
    int   i##e  = (int)u##e; \
    float fr##e = u##e - (float)i##e;

#define GLOAD(e) \
    ushort4 wa##e = *(const ushort4*)&Wtb[(size_t)i##e * CDIM + c4]; \
    ushort4 wb##e = *(const ushort4*)&Wtb[(size_t)i##e * CDIM + CDIM + c4]; \
    ushort4 fx##e = *(const ushort4*)&xw3h[(size_t)s##e * CDIM + c4];

#define GFMA(e) { \
    float a0 = bf2f(wa##e.x), b0 = bf2f(wb##e.x); \
    float a1 = bf2f(wa##e.y), b1v = bf2f(wb##e.y); \
    float a2 = bf2f(wa##e.z), b2v = bf2f(wb##e.z); \
    float a3 = bf2f(wa##e.w), b3 = bf2f(wb##e.w); \
    acc.x = fmaf(fmaf(fr##e, b0 - a0, a0),  bf2f(fx##e.x), acc.x); \
    acc.y = fmaf(fmaf(fr##e, b1v - a1, a1), bf2f(fx##e.y), acc.y); \
    acc.z = fmaf(fmaf(fr##e, b2v - a2, a2), bf2f(fx##e.z), acc.z); \
    acc.w = fmaf(fmaf(fr##e, b3 - a3, a3),  bf2f(fx##e.w), acc.w); }

__global__ __launch_bounds__(NTHR, 4)
void gather_kernel(const int* __restrict__ cnt,
                   const int2* __restrict__ slots,
                   const unsigned short* __restrict__ Wtb,
                   const unsigned short* __restrict__ xw3h,
                   float* __restrict__ conv)
{
    const int t = threadIdx.x;
    const int n = blockIdx.x * 4 + (t >> 6);
    const int l = t & 63;
    const int c4 = l * 4;
    const int2* sl = slots + (size_t)n * CAP;
    int deg = cnt[n];
    deg = deg > CAP ? CAP : deg;

    float4 acc = make_float4(0.0f, 0.0f, 0.0f, 0.0f);

    int j = 0;
    int2 dsc = (deg >= 8) ? sl[l & 7] : make_int2(0, 0);

    while (j + 8 <= deg) {
        GDESC(0, dsc) GDESC(1, dsc) GDESC(2, dsc) GDESC(3, dsc)
        GDESC(4, dsc) GDESC(5, dsc) GDESC(6, dsc) GDESC(7, dsc)
        if (j + 16 <= deg) dsc = sl[j + 8 + (l & 7)];   // prefetch next batch descriptors
        GLOAD(0) GLOAD(1) GLOAD(2) GLOAD(3)
        GLOAD(4) GLOAD(5) GLOAD(6) GLOAD(7)
        GFMA(0) GFMA(1) GFMA(2) GFMA(3)
        GFMA(4) GFMA(5) GFMA(6) GFMA(7)
        j += 8;
    }

    if (j + 4 <= deg) {
        int2 d4 = sl[j + (l & 3)];
        GDESC(0, d4) GDESC(1, d4) GDESC(2, d4) GDESC(3, d4)
        GLOAD(0) GLOAD(1) GLOAD(2) GLOAD(3)
        GFMA(0) GFMA(1) GFMA(2) GFMA(3)
        j += 4;
    }

    // serial tail (<= 3 edges): issue loads first, then FMAs
    {
        int rem = deg - j;
        if (rem > 0) {
            int2 sv0 = sl[j];
            GDESC(0, sv0)
            GLOAD(0)
            if (rem > 1) {
                int2 sv1 = sl[j + 1];
                GDESC(1, sv1)
                GLOAD(1)
                if (rem > 2) {
                    int2 sv2 = sl[j + 2];
                    GDESC(2, sv2)
                    GLOAD(2)
                    GFMA(2)
                }
                GFMA(1)
            }
            GFMA(0)
        }
    }

    *(float4*)&conv[(size_t)n * CDIM + c4] = acc;
}

// ---------- node MLP (MFMA, 32-row tiles): out = x + ssp(conv@w4+b4) @ w5 + b5 -----
__global__ __launch_bounds__(NTHR, 4)
void node_kernel(const float* __restrict__ conv,
                 const unsigned short* __restrict__ w4p, const float* __restrict__ b4,
                 const unsigned short* __restrict__ w5p, const float* __restrict__ b5,
                 const float* __restrict__ x,
                 float* __restrict__ out)
{
    __shared__ unsigned short s_a[NR * RS];      // 16896 B -> up to 4 blocks/CU
    const int t = threadIdx.x;
    const int m0 = blockIdx.x * NR;              // NNODES % 32 == 0 -> no row guards

    {
        int row = t >> 3;
        const float* src = &conv[(size_t)(m0 + row) * CDIM];
        unsigned short* dst = &s_a[row * RS];
        #pragma unroll
        for (int oc = 0; oc < 4; ++oc) {
            int c0 = oc * 64 + (t & 7) * 8;
            float4 a = *(const float4*)&src[c0];
            float4 b = *(const float4*)&src[c0 + 4];
            u16x8 v;
            v[0] = f2bf(a.x); v[1] = f2bf(a.y); v[2] = f2bf(a.z); v[3] = f2bf(a.w);
            v[4] = f2bf(b.x); v[5] = f2bf(b.y); v[6] = f2bf(b.z); v[7] = f2bf(b.w);
            *(u16x8*)&dst[c0] = v;
        }
    }
    __syncthreads();

    const int l = t & 63, w = t >> 6, lr = l & 15, lg = l >> 4, nb = w * 64;
    f32x4 acc[2][4];
    #pragma unroll
    for (int mt = 0; mt < 2; ++mt)
        #pragma unroll
        for (int nt = 0; nt < 4; ++nt) acc[mt][nt] = (f32x4)0.0f;

    #pragma unroll 2
    for (int kt = 0; kt < 8; ++kt) {
        bf16x8 a[2];
        #pragma unroll
        for (int mt = 0; mt < 2; ++mt)
            a[mt] = *(const bf16x8*)&s_a[(mt * 16 + lr) * RS + kt * 32 + lg * 8];
        #pragma unroll
        for (int nt = 0; nt < 4; ++nt) {
            bf16x8 b = *(const bf16x8*)&w4p[(size_t)(((kt * 4 + lg) * 256) + nb + nt * 16 + lr) * 8];
            #pragma unroll
            for (int mt = 0; mt < 2; ++mt)
                acc[mt][nt] = __builtin_amdgcn_mfma_f32_16x16x32_bf16(a[mt], b, acc[mt][nt], 0, 0, 0);
        }
    }
    __syncthreads();

    #pragma unroll
    for (int nt = 0; nt < 4; ++nt) {
        int col = nb + nt * 16 + lr;
        float bias = b4[col];
        #pragma unroll
        for (int mt = 0; mt < 2; ++mt)
            #pragma unroll
            for (int rr = 0; rr < 4; ++rr)
                s_a[(mt * 16 + lg * 4 + rr) * RS + col] = f2bf(ssp_f(acc[mt][nt][rr] + bias));
    }
    __syncthreads();

    #pragma unroll
    for (int mt = 0; mt < 2; ++mt)
        #pragma unroll
        for (int nt = 0; nt < 4; ++nt) acc[mt][nt] = (f32x4)0.0f;

    #pragma unroll 2
    for (int kt = 0; kt < 8; ++kt) {
        bf16x8 a[2];
        #pragma unroll
        for (int mt = 0; mt < 2; ++mt)
            a[mt] = *(const bf16x8*)&s_a[(mt * 16 + lr) * RS + kt * 32 + lg * 8];
        #pragma unroll
        for (int nt = 0; nt < 4; ++nt) {
            bf16x8 b = *(const bf16x8*)&w5p[(size_t)(((kt * 4 + lg) * 256) + nb + nt * 16 + lr) * 8];
            #pragma unroll
            for (int mt = 0; mt < 2; ++mt)
                acc[mt][nt] = __builtin_amdgcn_mfma_f32_16x16x32_bf16(a[mt], b, acc[mt][nt], 0, 0, 0);
        }
    }

    #pragma unroll
    for (int nt = 0; nt < 4; ++nt) {
        int col = nb + nt * 16 + lr;
        float bias = b5[col];
        #pragma unroll
        for (int mt = 0; mt < 2; ++mt)
            #pragma unroll
            for (int rr = 0; rr < 4; ++rr) {
                int row = m0 + mt * 16 + lg * 4 + rr;
                out[(size_t)row * CDIM + col] =
                    acc[mt][nt][rr] + bias + x[(size_t)row * CDIM + col];
            }
    }
}

extern "C" void kernel_launch(void* const* d_in, const int* in_sizes, int n_in,
                              void* d_out, int out_size, void* d_ws, size_t ws_size,
                              hipStream_t stream) {
    const float* pos = (const float*)d_in[0];
    const float* x   = (const float*)d_in[1];
    const int*   snd = (const int*)d_in[2];
    const int*   rcv = (const int*)d_in[3];
    const float* w1  = (const float*)d_in[4];
    const float* b1  = (const float*)d_in[5];
    const float* w2  = (const float*)d_in[6];
    const float* b2  = (const float*)d_in[7];
    const float* w3  = (const float*)d_in[8];
    const float* w4  = (const float*)d_in[9];
    const float* b4  = (const float*)d_in[10];
    const float* w5  = (const float*)d_in[11];
    const float* b5  = (const float*)d_in[12];

    float* out  = (float*)d_out;
    float* conv = out;    // gather writes every conv row exactly once (f32, non-atomic)

    // ws: xw3h bf16 | Wtb bf16 2112x256 | w3p/w4p/w5p | w1p | w2p | cnt | slots
    unsigned char* ws = (unsigned char*)d_ws;
    unsigned short* xw3h = (unsigned short*)ws;
    size_t off = (size_t)NNODES * CDIM * 2;
    unsigned short* Wtb = (unsigned short*)(ws + off); off += (size_t)TROWS * CDIM * 2;
    unsigned short* w3p = (unsigned short*)(ws + off); off += 65536 * 2;
    unsigned short* w4p = (unsigned short*)(ws + off); off += 65536 * 2;
    unsigned short* w5p = (unsigned short*)(ws + off); off += 65536 * 2;
    unsigned short* w1p = (unsigned short*)(ws + off); off += 57344 * 2;
    unsigned short* w2p = (unsigned short*)(ws + off); off += 65536 * 2;
    int* cnt = (int*)(ws + off);                       off += (size_t)NNODES * 4;
    int2* slots = (int2*)(ws + off);

    zero_kernel<<<(NNODES / 4 + NTHR - 1) / NTHR, NTHR, 0, stream>>>((int4*)cnt);
    fillpack_kernel<<<FILLB + PACKB, NTHR, 0, stream>>>(pos, snd, rcv, cnt, slots,
                                                        w3, w4, w5, w1, w2,
                                                        w3p, w4p, w5p, w1p, w2p);
    tablexw3_kernel<<<TBLK + XW3B, NTHR, 0, stream>>>(w1p, b1, w2p, b2, Wtb, x, w3p, xw3h);
    gather_kernel<<<NNODES / 4, NTHR, 0, stream>>>(cnt, slots, Wtb, xw3h, conv);
    node_kernel<<<NODEB, NTHR, 0, stream>>>(conv, w4p, b4, w5p, b5, x, out);
}